// Round 1
// baseline (898.056 us; speedup 1.0000x reference)
//
#include <hip/hip_runtime.h>
#include <hip/hip_bf16.h>
#include <math.h>

// Problem constants (match reference)
#define V_SIZE 100000
#define D_DIM  256
#define S_DIM  128
#define H_DIM  512
#define B_SIZE 8192
#define K_NEG  32
#define NR     60000           // NUM_REGULAR
#define NMOD   (V_SIZE - NR)   // 40000 modified words

// ---------------------------------------------------------------------------
// MLP table precompute: out[w] = relu(stoich[NR+w] @ w1 + b1) @ w2 + b2
// for w in [0, NMOD). One block computes MLP_ROWS rows.
// ---------------------------------------------------------------------------
#define MLP_ROWS 16

__global__ __launch_bounds__(256) void mlp_table_kernel(
    const float* __restrict__ stoich,   // [V, S]
    const float* __restrict__ w1,       // [S, H]
    const float* __restrict__ b1,       // [H]
    const float* __restrict__ w2,       // [H, D]
    const float* __restrict__ b2,       // [D]
    float* __restrict__ out)            // [NMOD, D]
{
    __shared__ float s_x[MLP_ROWS][S_DIM];   // 16*128*4 = 8 KiB
    __shared__ float s_h[MLP_ROWS][H_DIM];   // 16*512*4 = 32 KiB

    const int tid  = threadIdx.x;            // 256 threads
    const int row0 = blockIdx.x * MLP_ROWS;  // within [0, NMOD)

    // stage stoich rows
    for (int i = tid; i < MLP_ROWS * S_DIM; i += 256) {
        int r = i >> 7, s = i & (S_DIM - 1);
        s_x[r][s] = stoich[(size_t)(NR + row0 + r) * S_DIM + s];
    }
    __syncthreads();

    // layer 1: each thread owns hidden columns h = tid and tid+256
    float acc0[MLP_ROWS], acc1[MLP_ROWS];
    #pragma unroll
    for (int r = 0; r < MLP_ROWS; ++r) { acc0[r] = 0.f; acc1[r] = 0.f; }

    #pragma unroll 4
    for (int s = 0; s < S_DIM; ++s) {
        float wv0 = w1[(size_t)s * H_DIM + tid];
        float wv1 = w1[(size_t)s * H_DIM + tid + 256];
        #pragma unroll
        for (int r = 0; r < MLP_ROWS; ++r) {
            float xv = s_x[r][s];
            acc0[r] = fmaf(xv, wv0, acc0[r]);
            acc1[r] = fmaf(xv, wv1, acc1[r]);
        }
    }
    float bb0 = b1[tid], bb1 = b1[tid + 256];
    #pragma unroll
    for (int r = 0; r < MLP_ROWS; ++r) {
        s_h[r][tid]       = fmaxf(acc0[r] + bb0, 0.f);
        s_h[r][tid + 256] = fmaxf(acc1[r] + bb1, 0.f);
    }
    __syncthreads();

    // layer 2: each thread owns output column d = tid
    float o[MLP_ROWS];
    #pragma unroll
    for (int r = 0; r < MLP_ROWS; ++r) o[r] = 0.f;

    #pragma unroll 4
    for (int h = 0; h < H_DIM; ++h) {
        float wv = w2[(size_t)h * D_DIM + tid];
        #pragma unroll
        for (int r = 0; r < MLP_ROWS; ++r)
            o[r] = fmaf(s_h[r][h], wv, o[r]);
    }
    float bv = b2[tid];
    for (int r = 0; r < MLP_ROWS; ++r)
        out[(size_t)(row0 + r) * D_DIM + tid] = o[r] + bv;
}

// ---------------------------------------------------------------------------
// Scoring: one wave per sample b.
// total_b = 2*( -logsig(clip(eu.ev)) - sum_k logsig(-clip(env_k.eu)) )
// out[0] = mean_b total_b  (accumulated via atomicAdd of block partials)
// ---------------------------------------------------------------------------
__device__ __forceinline__ float logsig(float x) {
    // numerically stable log(sigmoid(x)) = min(x,0) - log1p(exp(-|x|))
    return fminf(x, 0.f) - log1pf(expf(-fabsf(x)));
}

__global__ __launch_bounds__(256) void score_kernel(
    const int*   __restrict__ pos_u,
    const int*   __restrict__ pos_v,
    const int*   __restrict__ neg_v,
    const float* __restrict__ u_emb,
    const float* __restrict__ v_emb,
    const float* __restrict__ tab_t,   // [NMOD, D]
    const float* __restrict__ tab_c,   // [NMOD, D]
    float* __restrict__ out)
{
    const int tid  = threadIdx.x;
    const int lane = tid & 63;
    const int w    = tid >> 6;                  // wave id in block (0..3)
    const int b    = blockIdx.x * 4 + w;        // sample index

    int pu = pos_u[b];
    const float* eup = (pu < NR) ? (u_emb + (size_t)pu * D_DIM)
                                 : (tab_t + (size_t)(pu - NR) * D_DIM);
    float4 eu = ((const float4*)eup)[lane];

    int pv = pos_v[b];
    const float* evp = (pv < NR) ? (v_emb + (size_t)pv * D_DIM)
                                 : (tab_c + (size_t)(pv - NR) * D_DIM);
    float4 ev = ((const float4*)evp)[lane];

    float pd = eu.x*ev.x + eu.y*ev.y + eu.z*ev.z + eu.w*ev.w;
    #pragma unroll
    for (int o = 32; o; o >>= 1) pd += __shfl_xor(pd, o, 64);
    float p   = fminf(fmaxf(pd, -10.f), 10.f);
    float tot = -logsig(p);

    const int* nvp = neg_v + (size_t)b * K_NEG;
    float nsum = 0.f;
    #pragma unroll 4
    for (int k = 0; k < K_NEG; ++k) {
        int ix = nvp[k];
        const float* np_ = (ix < NR) ? (v_emb + (size_t)ix * D_DIM)
                                     : (tab_c + (size_t)(ix - NR) * D_DIM);
        float4 nv = ((const float4*)np_)[lane];
        float d = eu.x*nv.x + eu.y*nv.y + eu.z*nv.z + eu.w*nv.w;
        #pragma unroll
        for (int o = 32; o; o >>= 1) d += __shfl_xor(d, o, 64);
        float n = fminf(fmaxf(d, -10.f), 10.f);
        nsum += logsig(-n);
    }
    tot -= nsum;

    __shared__ float ws4[4];
    if (lane == 0) ws4[w] = tot;
    __syncthreads();
    if (tid == 0) {
        float s = ws4[0] + ws4[1] + ws4[2] + ws4[3];
        atomicAdd(out, s * (2.0f / (float)B_SIZE));
    }
}

// ---------------------------------------------------------------------------
extern "C" void kernel_launch(void* const* d_in, const int* in_sizes, int n_in,
                              void* d_out, int out_size, void* d_ws, size_t ws_size,
                              hipStream_t stream) {
    const int*   pos_u  = (const int*)  d_in[0];
    const int*   pos_v  = (const int*)  d_in[1];
    const int*   neg_v  = (const int*)  d_in[2];
    const float* u_emb  = (const float*)d_in[3];
    const float* v_emb  = (const float*)d_in[4];
    const float* stoich = (const float*)d_in[5];
    const float* tw1    = (const float*)d_in[6];
    const float* tb1    = (const float*)d_in[7];
    const float* tw2    = (const float*)d_in[8];
    const float* tb2    = (const float*)d_in[9];
    const float* cw1    = (const float*)d_in[10];
    const float* cb1    = (const float*)d_in[11];
    const float* cw2    = (const float*)d_in[12];
    const float* cb2    = (const float*)d_in[13];
    float* out = (float*)d_out;

    // workspace: two fp32 tables [NMOD, D]
    float* tab_t = (float*)d_ws;
    float* tab_c = tab_t + (size_t)NMOD * D_DIM;

    hipMemsetAsync(out, 0, sizeof(float), stream);

    dim3 blk(256);
    dim3 grid_mlp(NMOD / MLP_ROWS);   // 2500
    mlp_table_kernel<<<grid_mlp, blk, 0, stream>>>(stoich, tw1, tb1, tw2, tb2, tab_t);
    mlp_table_kernel<<<grid_mlp, blk, 0, stream>>>(stoich, cw1, cb1, cw2, cb2, tab_c);

    dim3 grid_score(B_SIZE / 4);      // 2048 blocks, 4 waves each
    score_kernel<<<grid_score, blk, 0, stream>>>(pos_u, pos_v, neg_v,
                                                 u_emb, v_emb, tab_t, tab_c, out);
}

// Round 2
// 441.849 us; speedup vs baseline: 2.0325x; 2.0325x over previous
//
#include <hip/hip_runtime.h>
#include <hip/hip_bf16.h>
#include <math.h>

// Problem constants (match reference)
#define V_SIZE 100000
#define D_DIM  256
#define S_DIM  128
#define H_DIM  512
#define B_SIZE 8192
#define K_NEG  32
#define NR     60000           // NUM_REGULAR
#define NMOD   (V_SIZE - NR)   // 40000 modified words

typedef __attribute__((ext_vector_type(8))) short bf16x8;   // 8 bf16 = 4 VGPRs
typedef __attribute__((ext_vector_type(4))) float f32x4;

static __device__ __forceinline__ short f2bf(float f) {
    unsigned u = __builtin_bit_cast(unsigned, f);
    unsigned r = (u + 0x7fffu + ((u >> 16) & 1u)) >> 16;   // RNE
    return (short)r;
}
static __device__ __forceinline__ float bf2f(short s) {
    unsigned u = ((unsigned)(unsigned short)s) << 16;
    return __builtin_bit_cast(float, u);
}

// ---------------------------------------------------------------------------
// Conversion kernels (tiny)
// ---------------------------------------------------------------------------
// Xbf[t] = bf16(stoich[NR*S + t]), t in [0, NMOD*S), vectorized by 4
__global__ __launch_bounds__(256) void convert_x_kernel(
    const float* __restrict__ stoich, short* __restrict__ xbf)
{
    int t4 = blockIdx.x * 256 + threadIdx.x;          // [0, NMOD*S/4)
    const float4 v = ((const float4*)(stoich + (size_t)NR * S_DIM))[t4];
    short4 o;
    o.x = f2bf(v.x); o.y = f2bf(v.y); o.z = f2bf(v.z); o.w = f2bf(v.w);
    ((short4*)xbf)[t4] = o;
}

// out[n*K + k] = bf16(in[k*N + n])   (transpose + convert), K*N threads
__global__ __launch_bounds__(256) void transpose_w_kernel(
    const float* __restrict__ in, short* __restrict__ out, int K, int N)
{
    int t = blockIdx.x * 256 + threadIdx.x;
    if (t >= K * N) return;
    int n = t / K, k = t - n * K;
    out[t] = f2bf(in[(size_t)k * N + n]);
}

// ---------------------------------------------------------------------------
// MFMA GEMM: C[M][N] = relu?(A[M][K] @ B[K][N] + bias), A/BT/C bf16, acc fp32
// BT is B transposed: [N][K].  Block = 4 waves; wave tile 64x64; block tile
// 64 x 256.  Fragments loaded directly from global (B is L2-resident,
// A reads are 16 rows x 64B contiguous -> line-perfect).
// Verified layouts (m89/m91): A[m=lane&15][k=quad*8+j]; B[k=quad*8+j][n=lane&15];
// D: col=lane&15, row=quad*4+reg.
// ---------------------------------------------------------------------------
template<int K, bool RELU>
__global__ __launch_bounds__(256) void gemm_kernel(
    const short* __restrict__ A,     // [M][K] bf16
    const short* __restrict__ BT,    // [N][K] bf16
    const float* __restrict__ bias,  // [N]
    short* __restrict__ C,           // [M][N] bf16
    int N)
{
    const int lane = threadIdx.x & 63;
    const int wv   = threadIdx.x >> 6;
    const int m0   = blockIdx.x * 64;
    const int n0   = blockIdx.y * 256 + wv * 64;
    const int fr   = lane & 15;      // fragment row (m for A, n for B, col for D)
    const int q    = lane >> 4;      // quad

    const short* Ap = A  + (size_t)(m0 + fr) * K + q * 8;
    const short* Bp = BT + (size_t)(n0 + fr) * K + q * 8;

    f32x4 acc[4][4] = {};

    #pragma unroll 4
    for (int ks = 0; ks < K / 32; ++ks) {
        bf16x8 a[4], b[4];
        #pragma unroll
        for (int i = 0; i < 4; ++i) {
            a[i] = *(const bf16x8*)(Ap + (size_t)i * 16 * K + ks * 32);
            b[i] = *(const bf16x8*)(Bp + (size_t)i * 16 * K + ks * 32);
        }
        #pragma unroll
        for (int mi = 0; mi < 4; ++mi)
            #pragma unroll
            for (int ni = 0; ni < 4; ++ni)
                acc[mi][ni] = __builtin_amdgcn_mfma_f32_16x16x32_bf16(
                    a[mi], b[ni], acc[mi][ni], 0, 0, 0);
    }

    #pragma unroll
    for (int ni = 0; ni < 4; ++ni) {
        int c = n0 + ni * 16 + fr;
        float bv = bias[c];
        #pragma unroll
        for (int mi = 0; mi < 4; ++mi) {
            #pragma unroll
            for (int r = 0; r < 4; ++r) {
                int row = m0 + mi * 16 + q * 4 + r;
                float v = acc[mi][ni][r] + bv;
                if (RELU) v = fmaxf(v, 0.f);
                C[(size_t)row * N + c] = f2bf(v);
            }
        }
    }
}

// ---------------------------------------------------------------------------
// Scoring: one block (4 waves) per sample. Wave w handles negatives
// [w*8, w*8+8); wave 0 also does the pos term. Partial per block -> ws array.
// total_b = 2*( -logsig(clip(eu.ev)) - sum_k logsig(-clip(env_k.eu)) )
// ---------------------------------------------------------------------------
__device__ __forceinline__ float logsig(float x) {
    return fminf(x, 0.f) - log1pf(expf(-fabsf(x)));
}
__device__ __forceinline__ float clip10(float x) {
    return fminf(fmaxf(x, -10.f), 10.f);
}
__device__ __forceinline__ float dot4(float4 a, float4 b) {
    return a.x * b.x + a.y * b.y + a.z * b.z + a.w * b.w;
}
__device__ __forceinline__ float reduce64(float v) {
    #pragma unroll
    for (int o = 32; o; o >>= 1) v += __shfl_xor(v, o, 64);
    return v;
}
__device__ __forceinline__ float4 ld_f32(const float* base, int row, int lane) {
    return ((const float4*)(base + (size_t)row * D_DIM))[lane];
}
__device__ __forceinline__ float4 ld_bf16(const short* base, int row, int lane) {
    short4 s = ((const short4*)(base + (size_t)row * D_DIM))[lane];
    return make_float4(bf2f(s.x), bf2f(s.y), bf2f(s.z), bf2f(s.w));
}

__global__ __launch_bounds__(256) void score_kernel(
    const int*   __restrict__ pos_u,
    const int*   __restrict__ pos_v,
    const int*   __restrict__ neg_v,
    const float* __restrict__ u_emb,
    const float* __restrict__ v_emb,
    const short* __restrict__ tab_t,   // [NMOD, D] bf16
    const short* __restrict__ tab_c,   // [NMOD, D] bf16
    float* __restrict__ partials)      // [B]
{
    const int b    = blockIdx.x;
    const int lane = threadIdx.x & 63;
    const int wv   = threadIdx.x >> 6;

    int pu = pos_u[b];
    float4 eu = (pu < NR) ? ld_f32(u_emb, pu, lane)
                          : ld_bf16(tab_t, pu - NR, lane);

    float part = 0.f;
    if (wv == 0) {
        int pv = pos_v[b];
        float4 ev = (pv < NR) ? ld_f32(v_emb, pv, lane)
                              : ld_bf16(tab_c, pv - NR, lane);
        float pd = reduce64(dot4(eu, ev));
        part -= logsig(clip10(pd));
    }

    const int* nv = neg_v + (size_t)b * K_NEG + wv * 8;
    int idx[8];
    #pragma unroll
    for (int k = 0; k < 8; ++k) idx[k] = nv[k];
    float4 r[8];
    #pragma unroll
    for (int k = 0; k < 8; ++k)
        r[k] = (idx[k] < NR) ? ld_f32(v_emb, idx[k], lane)
                             : ld_bf16(tab_c, idx[k] - NR, lane);
    #pragma unroll
    for (int k = 0; k < 8; ++k) {
        float d = reduce64(dot4(eu, r[k]));
        part -= logsig(-clip10(d));
    }

    __shared__ float sp[4];
    if (lane == 0) sp[wv] = part;
    __syncthreads();
    if (threadIdx.x == 0)
        partials[b] = sp[0] + sp[1] + sp[2] + sp[3];
}

// partials[B] -> out[0] = mean * 2
__global__ __launch_bounds__(256) void reduce_kernel(
    const float* __restrict__ partials, float* __restrict__ out)
{
    float s = 0.f;
    for (int i = threadIdx.x; i < B_SIZE; i += 256) s += partials[i];
    s = reduce64(s);
    __shared__ float sp[4];
    if ((threadIdx.x & 63) == 0) sp[threadIdx.x >> 6] = s;
    __syncthreads();
    if (threadIdx.x == 0)
        out[0] = (sp[0] + sp[1] + sp[2] + sp[3]) * (2.0f / (float)B_SIZE);
}

// ---------------------------------------------------------------------------
extern "C" void kernel_launch(void* const* d_in, const int* in_sizes, int n_in,
                              void* d_out, int out_size, void* d_ws, size_t ws_size,
                              hipStream_t stream) {
    const int*   pos_u  = (const int*)  d_in[0];
    const int*   pos_v  = (const int*)  d_in[1];
    const int*   neg_v  = (const int*)  d_in[2];
    const float* u_emb  = (const float*)d_in[3];
    const float* v_emb  = (const float*)d_in[4];
    const float* stoich = (const float*)d_in[5];
    const float* tw1    = (const float*)d_in[6];
    const float* tb1    = (const float*)d_in[7];
    const float* tw2    = (const float*)d_in[8];
    const float* tb2    = (const float*)d_in[9];
    const float* cw1    = (const float*)d_in[10];
    const float* cb1    = (const float*)d_in[11];
    const float* cw2    = (const float*)d_in[12];
    const float* cb2    = (const float*)d_in[13];
    float* out = (float*)d_out;

    // workspace layout (bytes, all 16B aligned)
    char* ws = (char*)d_ws;
    short* Xbf    = (short*)(ws);                                   // 40000*128*2 = 10,240,000
    short* W1T_t  = (short*)(ws + 10240000);                        // 512*128*2   =    131,072
    short* W1T_c  = (short*)(ws + 10240000 + 131072);               //                 131,072
    short* W2T_t  = (short*)(ws + 10240000 + 262144);               // 256*512*2   =    262,144
    short* W2T_c  = (short*)(ws + 10240000 + 524288);               //                 262,144
    short* Hbf    = (short*)(ws + 11026432);                        // 40000*512*2 = 40,960,000
    short* tab_t  = (short*)(ws + 51986432);                        // 40000*256*2 = 20,480,000
    short* tab_c  = (short*)(ws + 72466432);                        //              20,480,000
    float* parts  = (float*)(ws + 92946432);                        // 8192*4      =     32,768

    dim3 blk(256);

    // conversions
    convert_x_kernel<<<dim3(NMOD * S_DIM / 4 / 256), blk, 0, stream>>>(stoich, Xbf);
    transpose_w_kernel<<<dim3((S_DIM * H_DIM + 255) / 256), blk, 0, stream>>>(tw1, W1T_t, S_DIM, H_DIM);
    transpose_w_kernel<<<dim3((S_DIM * H_DIM + 255) / 256), blk, 0, stream>>>(cw1, W1T_c, S_DIM, H_DIM);
    transpose_w_kernel<<<dim3((H_DIM * D_DIM + 255) / 256), blk, 0, stream>>>(tw2, W2T_t, H_DIM, D_DIM);
    transpose_w_kernel<<<dim3((H_DIM * D_DIM + 255) / 256), blk, 0, stream>>>(cw2, W2T_c, H_DIM, D_DIM);

    // MLP tables via MFMA GEMMs (sequential; Hbf reused)
    dim3 g1(NMOD / 64, H_DIM / 256);   // 625 x 2
    dim3 g2(NMOD / 64, D_DIM / 256);   // 625 x 1
    gemm_kernel<S_DIM, true ><<<g1, blk, 0, stream>>>(Xbf, W1T_t, tb1, Hbf,   H_DIM);
    gemm_kernel<H_DIM, false><<<g2, blk, 0, stream>>>(Hbf, W2T_t, tb2, tab_t, D_DIM);
    gemm_kernel<S_DIM, true ><<<g1, blk, 0, stream>>>(Xbf, W1T_c, cb1, Hbf,   H_DIM);
    gemm_kernel<H_DIM, false><<<g2, blk, 0, stream>>>(Hbf, W2T_c, cb2, tab_c, D_DIM);

    // scoring
    score_kernel<<<dim3(B_SIZE), blk, 0, stream>>>(pos_u, pos_v, neg_v,
                                                   u_emb, v_emb, tab_t, tab_c, parts);
    reduce_kernel<<<dim3(1), blk, 0, stream>>>(parts, out);
}

// Round 3
// 359.793 us; speedup vs baseline: 2.4960x; 1.2281x over previous
//
#include <hip/hip_runtime.h>
#include <hip/hip_bf16.h>
#include <math.h>

// Problem constants (match reference)
#define V_SIZE 100000
#define D_DIM  256
#define S_DIM  128
#define H_DIM  512
#define B_SIZE 8192
#define K_NEG  32
#define NR     60000           // NUM_REGULAR
#define NMOD   (V_SIZE - NR)   // 40000 modified words

typedef __attribute__((ext_vector_type(8))) short bf16x8;   // 8 bf16 = 4 VGPRs
typedef __attribute__((ext_vector_type(4))) float f32x4;

static __device__ __forceinline__ short f2bf(float f) {
    unsigned u = __builtin_bit_cast(unsigned, f);
    unsigned r = (u + 0x7fffu + ((u >> 16) & 1u)) >> 16;   // RNE
    return (short)r;
}

// ---------------------------------------------------------------------------
// Conversion / gather kernels (tiny)
// ---------------------------------------------------------------------------
// Xbf[t] = bf16(stoich[NR*S + t]), vectorized by 4
__global__ __launch_bounds__(256) void convert_x_kernel(
    const float* __restrict__ stoich, short* __restrict__ xbf)
{
    int t4 = blockIdx.x * 256 + threadIdx.x;          // [0, NMOD*S/4)
    const float4 v = ((const float4*)(stoich + (size_t)NR * S_DIM))[t4];
    short4 o;
    o.x = f2bf(v.x); o.y = f2bf(v.y); o.z = f2bf(v.z); o.w = f2bf(v.w);
    ((short4*)xbf)[t4] = o;
}

// Xu[b][:] = bf16(stoich[pos_u[b]][:]), one thread per 4 elems
__global__ __launch_bounds__(256) void gather_xu_kernel(
    const float* __restrict__ stoich, const int* __restrict__ pos_u,
    short* __restrict__ xu)
{
    int t = blockIdx.x * 256 + threadIdx.x;           // [0, B*S/4)
    int b = t >> 5, j = t & 31;                       // S/4 = 32 chunks per row
    int pu = pos_u[b];
    const float4 v = *(const float4*)(stoich + (size_t)pu * S_DIM + j * 4);
    short4 o;
    o.x = f2bf(v.x); o.y = f2bf(v.y); o.z = f2bf(v.z); o.w = f2bf(v.w);
    ((short4*)xu)[t] = o;
}

// out[n*K + k] = bf16(in[k*N + n])   (transpose + convert), K*N threads
__global__ __launch_bounds__(256) void transpose_w_kernel(
    const float* __restrict__ in, short* __restrict__ out, int K, int N)
{
    int t = blockIdx.x * 256 + threadIdx.x;
    if (t >= K * N) return;
    int n = t / K, k = t - n * K;
    out[t] = f2bf(in[(size_t)k * N + n]);
}

// ---------------------------------------------------------------------------
// Fused 2-layer MLP, MFMA, H tile in LDS (never hits HBM).
// out[M][256] fp32 = relu(A[M][128] @ W1 + b1) @ W2 + b2
// W1T: [512][128] bf16 (transposed), W2T: [256][512] bf16 (transposed).
// Block = 4 waves, TM=32 rows. Wave layer1 cols [wv*128,+128) (2 halves of 64),
// layer2 cols [wv*64,+64).
// LDS H: [32][528] shorts -> row stride 264 dwords == 8 mod 32: uniform
// 8-access/bank on ds_read_b128; 1056 B row stride keeps 16B alignment.
// Verified MFMA layouts (m89/m91): A[m=lane&15][k=q*8+j]; B^T row (lane&15)
// supplies B[k][n=lane&15]; D: col=lane&15, row=q*4+reg.
// ---------------------------------------------------------------------------
#define TM 32
#define HPAD 528

__global__ __launch_bounds__(256, 2) void fused_mlp_kernel(
    const short* __restrict__ A,     // [M][128] bf16
    const short* __restrict__ W1T,   // [512][128] bf16
    const float* __restrict__ b1,    // [512]
    const short* __restrict__ W2T,   // [256][512] bf16
    const float* __restrict__ b2,    // [256]
    float* __restrict__ out)         // [M][256] fp32
{
    __shared__ short sH[TM * HPAD];  // 33,792 B

    const int lane = threadIdx.x & 63;
    const int wv   = threadIdx.x >> 6;
    const int m0   = blockIdx.x * TM;
    const int fr   = lane & 15;
    const int q    = lane >> 4;

    // ---- layer 1 ----
    const short* Ap = A + (size_t)(m0 + fr) * S_DIM + q * 8;
    bf16x8 a[4][2];
    #pragma unroll
    for (int ks = 0; ks < 4; ++ks)
        #pragma unroll
        for (int mi = 0; mi < 2; ++mi)
            a[ks][mi] = *(const bf16x8*)(Ap + (size_t)mi * 16 * S_DIM + ks * 32);

    #pragma unroll
    for (int half = 0; half < 2; ++half) {
        const int n0h = wv * 128 + half * 64;
        const short* Bp = W1T + (size_t)(n0h + fr) * S_DIM + q * 8;
        f32x4 acc[2][4] = {};
        #pragma unroll
        for (int ks = 0; ks < 4; ++ks) {
            bf16x8 bfr[4];
            #pragma unroll
            for (int ni = 0; ni < 4; ++ni)
                bfr[ni] = *(const bf16x8*)(Bp + (size_t)ni * 16 * S_DIM + ks * 32);
            #pragma unroll
            for (int mi = 0; mi < 2; ++mi)
                #pragma unroll
                for (int ni = 0; ni < 4; ++ni)
                    acc[mi][ni] = __builtin_amdgcn_mfma_f32_16x16x32_bf16(
                        a[ks][mi], bfr[ni], acc[mi][ni], 0, 0, 0);
        }
        #pragma unroll
        for (int ni = 0; ni < 4; ++ni) {
            int c = n0h + ni * 16 + fr;
            float bv = b1[c];
            #pragma unroll
            for (int mi = 0; mi < 2; ++mi)
                #pragma unroll
                for (int r = 0; r < 4; ++r) {
                    int row = mi * 16 + q * 4 + r;
                    sH[row * HPAD + c] = f2bf(fmaxf(acc[mi][ni][r] + bv, 0.f));
                }
        }
    }
    __syncthreads();

    // ---- layer 2 ----
    f32x4 acc2[2][4] = {};
    const short* B2p = W2T + (size_t)(wv * 64 + fr) * H_DIM + q * 8;
    #pragma unroll 4
    for (int ks = 0; ks < 16; ++ks) {
        bf16x8 a2[2], b2f[4];
        #pragma unroll
        for (int mi = 0; mi < 2; ++mi)
            a2[mi] = *(const bf16x8*)(&sH[(mi * 16 + fr) * HPAD + q * 8 + ks * 32]);
        #pragma unroll
        for (int ni = 0; ni < 4; ++ni)
            b2f[ni] = *(const bf16x8*)(B2p + (size_t)ni * 16 * H_DIM + ks * 32);
        #pragma unroll
        for (int mi = 0; mi < 2; ++mi)
            #pragma unroll
            for (int ni = 0; ni < 4; ++ni)
                acc2[mi][ni] = __builtin_amdgcn_mfma_f32_16x16x32_bf16(
                    a2[mi], b2f[ni], acc2[mi][ni], 0, 0, 0);
    }
    #pragma unroll
    for (int ni = 0; ni < 4; ++ni) {
        int c = wv * 64 + ni * 16 + fr;
        float bv = b2[c];
        #pragma unroll
        for (int mi = 0; mi < 2; ++mi)
            #pragma unroll
            for (int r = 0; r < 4; ++r) {
                int row = m0 + mi * 16 + q * 4 + r;
                out[(size_t)row * D_DIM + c] = acc2[mi][ni][r] + bv;
            }
    }
}

// ---------------------------------------------------------------------------
// Scoring. One block (4 waves) per sample. 16-lane dots: each wave processes
// 4 rows concurrently (g = lane>>4 picks row, l = lane&15 picks 16-float
// chunk). All-fp32 sources -> single non-divergent load path.
// total_b = 2*( -logsig(clip(eu.ev)) - sum_k logsig(-clip(env_k.eu)) )
// ---------------------------------------------------------------------------
__device__ __forceinline__ float logsig_fast(float x) {
    float t = __expf(-fabsf(x));                 // v_exp_f32 path
    return fminf(x, 0.f) - __logf(1.f + t);      // v_log_f32 path
}
__device__ __forceinline__ float clip10(float x) {
    return fminf(fmaxf(x, -10.f), 10.f);
}
__device__ __forceinline__ float dot4(float4 a, float4 b) {
    return a.x * b.x + a.y * b.y + a.z * b.z + a.w * b.w;
}

__global__ __launch_bounds__(256) void score_kernel(
    const int*   __restrict__ pos_u,
    const int*   __restrict__ pos_v,
    const int*   __restrict__ neg_v,
    const float* __restrict__ u_emb,
    const float* __restrict__ v_emb,
    const float* __restrict__ tab_c,   // [NMOD][256] fp32
    const float* __restrict__ Ubuf,    // [B][256] fp32 (per-sample u-MLP)
    float* __restrict__ partials)      // [B]
{
    const int b    = blockIdx.x;
    const int lane = threadIdx.x & 63;
    const int wv   = threadIdx.x >> 6;
    const int g    = lane >> 4;        // row within group of 4
    const int l    = lane & 15;        // chunk within row

    int pu = pos_u[b];
    const float* eup = (pu < NR) ? u_emb + (size_t)pu * D_DIM
                                 : Ubuf  + (size_t)b  * D_DIM;
    float4 eu[4];
    #pragma unroll
    for (int j = 0; j < 4; ++j)
        eu[j] = *(const float4*)(eup + l * 16 + j * 4);

    float part = 0.f;
    const int* nv = neg_v + (size_t)b * K_NEG + wv * 8;

    #pragma unroll
    for (int it = 0; it < 2; ++it) {
        int ix = nv[it * 4 + g];
        const float* rp = (ix < NR) ? v_emb + (size_t)ix * D_DIM
                                    : tab_c + (size_t)(ix - NR) * D_DIM;
        float d = 0.f;
        #pragma unroll
        for (int j = 0; j < 4; ++j)
            d += dot4(eu[j], *(const float4*)(rp + l * 16 + j * 4));
        #pragma unroll
        for (int o = 1; o < 16; o <<= 1) d += __shfl_xor(d, o, 64);
        part -= logsig_fast(-clip10(d));
    }

    if (wv == 0) {                       // pos term
        int pv = pos_v[b];
        const float* rp = (pv < NR) ? v_emb + (size_t)pv * D_DIM
                                    : tab_c + (size_t)(pv - NR) * D_DIM;
        float d = 0.f;
        #pragma unroll
        for (int j = 0; j < 4; ++j)
            d += dot4(eu[j], *(const float4*)(rp + l * 16 + j * 4));
        #pragma unroll
        for (int o = 1; o < 16; o <<= 1) d += __shfl_xor(d, o, 64);
        float term = -logsig_fast(clip10(d));
        if (g == 0) part += term;        // count once per l-lane
    }

    // each row's contribution is duplicated across 16 l-lanes
    float ws = part;
    #pragma unroll
    for (int o = 32; o; o >>= 1) ws += __shfl_xor(ws, o, 64);
    __shared__ float sp[4];
    if (lane == 0) sp[wv] = ws * 0.0625f;
    __syncthreads();
    if (threadIdx.x == 0)
        partials[b] = sp[0] + sp[1] + sp[2] + sp[3];
}

// partials[B] -> out[0] = mean * 2
__global__ __launch_bounds__(256) void reduce_kernel(
    const float* __restrict__ partials, float* __restrict__ out)
{
    float s = 0.f;
    for (int i = threadIdx.x; i < B_SIZE; i += 256) s += partials[i];
    #pragma unroll
    for (int o = 32; o; o >>= 1) s += __shfl_xor(s, o, 64);
    __shared__ float sp[4];
    if ((threadIdx.x & 63) == 0) sp[threadIdx.x >> 6] = s;
    __syncthreads();
    if (threadIdx.x == 0)
        out[0] = (sp[0] + sp[1] + sp[2] + sp[3]) * (2.0f / (float)B_SIZE);
}

// ---------------------------------------------------------------------------
extern "C" void kernel_launch(void* const* d_in, const int* in_sizes, int n_in,
                              void* d_out, int out_size, void* d_ws, size_t ws_size,
                              hipStream_t stream) {
    const int*   pos_u  = (const int*)  d_in[0];
    const int*   pos_v  = (const int*)  d_in[1];
    const int*   neg_v  = (const int*)  d_in[2];
    const float* u_emb  = (const float*)d_in[3];
    const float* v_emb  = (const float*)d_in[4];
    const float* stoich = (const float*)d_in[5];
    const float* tw1    = (const float*)d_in[6];
    const float* tb1    = (const float*)d_in[7];
    const float* tw2    = (const float*)d_in[8];
    const float* tb2    = (const float*)d_in[9];
    const float* cw1    = (const float*)d_in[10];
    const float* cb1    = (const float*)d_in[11];
    const float* cw2    = (const float*)d_in[12];
    const float* cb2    = (const float*)d_in[13];
    float* out = (float*)d_out;

    // workspace layout (bytes, 16B aligned)
    char* ws = (char*)d_ws;
    short* Xbf   = (short*)(ws);                      // 40000*128*2 = 10,240,000
    short* Xu    = (short*)(ws + 10240000);           //  8192*128*2 =  2,097,152
    short* W1T_t = (short*)(ws + 12337152);           //   512*128*2 =    131,072
    short* W1T_c = (short*)(ws + 12468224);           //                 131,072
    short* W2T_t = (short*)(ws + 12599296);           //   256*512*2 =    262,144
    short* W2T_c = (short*)(ws + 12861440);           //                 262,144
    float* tab_c = (float*)(ws + 13123584);           // 40000*256*4 = 40,960,000
    float* Ubuf  = (float*)(ws + 54083584);           //  8192*256*4 =  8,388,608
    float* parts = (float*)(ws + 62472192);           //  8192*4

    dim3 blk(256);

    // preprocessing (independent)
    convert_x_kernel<<<dim3(NMOD * S_DIM / 4 / 256), blk, 0, stream>>>(stoich, Xbf);
    gather_xu_kernel<<<dim3(B_SIZE * S_DIM / 4 / 256), blk, 0, stream>>>(stoich, pos_u, Xu);
    transpose_w_kernel<<<dim3((S_DIM * H_DIM + 255) / 256), blk, 0, stream>>>(tw1, W1T_t, S_DIM, H_DIM);
    transpose_w_kernel<<<dim3((S_DIM * H_DIM + 255) / 256), blk, 0, stream>>>(cw1, W1T_c, S_DIM, H_DIM);
    transpose_w_kernel<<<dim3((H_DIM * D_DIM + 255) / 256), blk, 0, stream>>>(tw2, W2T_t, H_DIM, D_DIM);
    transpose_w_kernel<<<dim3((H_DIM * D_DIM + 255) / 256), blk, 0, stream>>>(cw2, W2T_c, H_DIM, D_DIM);

    // fused MLPs: u-side on gathered rows (8192), c-side full table (40000)
    fused_mlp_kernel<<<dim3(B_SIZE / TM), blk, 0, stream>>>(Xu,  W1T_t, tb1, W2T_t, tb2, Ubuf);
    fused_mlp_kernel<<<dim3(NMOD  / TM), blk, 0, stream>>>(Xbf, W1T_c, cb1, W2T_c, cb2, tab_c);

    // scoring
    score_kernel<<<dim3(B_SIZE), blk, 0, stream>>>(pos_u, pos_v, neg_v,
                                                   u_emb, v_emb, tab_c, Ubuf, parts);
    reduce_kernel<<<dim3(1), blk, 0, stream>>>(parts, out);
}

// Round 4
// 324.108 us; speedup vs baseline: 2.7709x; 1.1101x over previous
//
#include <hip/hip_runtime.h>
#include <hip/hip_bf16.h>
#include <math.h>

// Problem constants (match reference)
#define V_SIZE 100000
#define D_DIM  256
#define S_DIM  128
#define H_DIM  512
#define B_SIZE 8192
#define K_NEG  32
#define NR     60000           // NUM_REGULAR
#define NMOD   (V_SIZE - NR)   // 40000 modified words

// MLP tiling
#define TM     48              // rows per block (3 x 16)
#define CBLK   834             // ceil(40000/48)
#define UBLK   171             // ceil(8192/48)
#define MC_PAD (CBLK * TM)     // 40032 padded c-side rows
#define MU_PAD (UBLK * TM)     // 8208  padded u-side rows
// LDS H row stride (shorts). 516: layer-1 b16 writes land 2 lanes/bank
// (free); 1032-B rows keep 8-B alignment for ds_read_b64 in layer 2.
#define HPAD   516

typedef __attribute__((ext_vector_type(8))) short bf16x8;   // 8 bf16 = 4 VGPRs
typedef __attribute__((ext_vector_type(4))) float f32x4;

static __device__ __forceinline__ short f2bf(float f) {
    unsigned u = __builtin_bit_cast(unsigned, f);
    unsigned r = (u + 0x7fffu + ((u >> 16) & 1u)) >> 16;   // RNE
    return (short)r;
}

// ---------------------------------------------------------------------------
// Prep kernels
// ---------------------------------------------------------------------------
// Xbf[0..MC_PAD*S) = bf16(stoich[NR..NR+NMOD)), pad rows zeroed. Quad-per-thread.
__global__ __launch_bounds__(256) void convert_x_kernel(
    const float* __restrict__ stoich, short* __restrict__ xbf)
{
    int t4 = blockIdx.x * 256 + threadIdx.x;          // [0, MC_PAD*S/4)
    short4 o = {0, 0, 0, 0};
    if (t4 < NMOD * S_DIM / 4) {
        const float4 v = ((const float4*)(stoich + (size_t)NR * S_DIM))[t4];
        o.x = f2bf(v.x); o.y = f2bf(v.y); o.z = f2bf(v.z); o.w = f2bf(v.w);
    }
    ((short4*)xbf)[t4] = o;
}

// Xu[b][:] = bf16(stoich[pos_u[b]][:]), pad rows zeroed
__global__ __launch_bounds__(256) void gather_xu_kernel(
    const float* __restrict__ stoich, const int* __restrict__ pos_u,
    short* __restrict__ xu)
{
    int t = blockIdx.x * 256 + threadIdx.x;           // [0, MU_PAD*S/4)
    int b = t >> 5, j = t & 31;                       // S/4 = 32 chunks per row
    short4 o = {0, 0, 0, 0};
    if (b < B_SIZE) {
        int pu = pos_u[b];
        const float4 v = *(const float4*)(stoich + (size_t)pu * S_DIM + j * 4);
        o.x = f2bf(v.x); o.y = f2bf(v.y); o.z = f2bf(v.z); o.w = f2bf(v.w);
    }
    ((short4*)xu)[t] = o;
}

// All four weight transposes (fp32 -> bf16, [K][N] -> [N][K]) in one launch.
__global__ __launch_bounds__(256) void transpose_all_kernel(
    const float* __restrict__ tw1, const float* __restrict__ cw1,
    const float* __restrict__ tw2, const float* __restrict__ cw2,
    short* __restrict__ W1T_t, short* __restrict__ W1T_c,
    short* __restrict__ W2T_t, short* __restrict__ W2T_c)
{
    int t = blockIdx.x * 256 + threadIdx.x;   // [0, 393216)
    if (t < 65536) {                // W1T_t: out[n*128+k] = tw1[k*512+n]
        int n = t >> 7, k = t & 127;
        W1T_t[t] = f2bf(tw1[(size_t)k * H_DIM + n]);
    } else if (t < 131072) {
        int t2 = t - 65536; int n = t2 >> 7, k = t2 & 127;
        W1T_c[t2] = f2bf(cw1[(size_t)k * H_DIM + n]);
    } else if (t < 262144) {        // W2T_t: out[n*512+k] = tw2[k*256+n]
        int t2 = t - 131072; int n = t2 >> 9, k = t2 & 511;
        W2T_t[t2] = f2bf(tw2[(size_t)k * D_DIM + n]);
    } else {
        int t2 = t - 262144; int n = t2 >> 9, k = t2 & 511;
        W2T_c[t2] = f2bf(cw2[(size_t)k * D_DIM + n]);
    }
}

// ---------------------------------------------------------------------------
// Fused 2-layer MLP (c-side table + u-side gathered rows in one launch).
// out[M][256] fp32 = relu(A[M][128] @ W1 + b1) @ W2 + b2
// Block = 4 waves, TM=48 rows. Layer 1: wave owns 128 H-cols (2 halves of
// 64). Layer 2: wave owns 64 out-cols, register double-buffered fragment
// prefetch over the 16 K-steps.
// Verified MFMA layouts (m89/m91): A[m=lane&15][k=q*8+j]; B^T row (lane&15)
// supplies B[k][n=lane&15]; D: col=lane&15, row=q*4+reg.
// ---------------------------------------------------------------------------
__global__ __launch_bounds__(256, 3) void fused_mlp_kernel(
    const short* __restrict__ Xc,  const short* __restrict__ W1c,
    const float* __restrict__ b1c, const short* __restrict__ W2c,
    const float* __restrict__ b2c, float* __restrict__ outc,
    const short* __restrict__ Xu,  const short* __restrict__ W1u,
    const float* __restrict__ b1u, const short* __restrict__ W2u,
    const float* __restrict__ b2u, float* __restrict__ outu)
{
    __shared__ short sH[TM * HPAD];   // 49,536 B -> 3 blocks/CU

    const int blk = blockIdx.x;
    const short *A, *W1T, *W2T; const float *b1, *b2; float* out; int m0;
    if (blk < CBLK) { A = Xc; W1T = W1c; b1 = b1c; W2T = W2c; b2 = b2c;
                      out = outc; m0 = blk * TM; }
    else            { A = Xu; W1T = W1u; b1 = b1u; W2T = W2u; b2 = b2u;
                      out = outu; m0 = (blk - CBLK) * TM; }

    const int lane = threadIdx.x & 63;
    const int wv   = threadIdx.x >> 6;
    const int fr   = lane & 15;
    const int q    = lane >> 4;

    // ---- layer 1 ----
    const short* Ap = A + (size_t)(m0 + fr) * S_DIM + q * 8;
    bf16x8 af[4][3];
    #pragma unroll
    for (int ks = 0; ks < 4; ++ks)
        #pragma unroll
        for (int mi = 0; mi < 3; ++mi)
            af[ks][mi] = *(const bf16x8*)(Ap + mi * 16 * S_DIM + ks * 32);

    #pragma unroll
    for (int half = 0; half < 2; ++half) {
        const int n0h = wv * 128 + half * 64;
        const short* Bp = W1T + (size_t)(n0h + fr) * S_DIM + q * 8;
        f32x4 acc[3][4] = {};
        #pragma unroll
        for (int ks = 0; ks < 4; ++ks) {
            bf16x8 bfr[4];
            #pragma unroll
            for (int ni = 0; ni < 4; ++ni)
                bfr[ni] = *(const bf16x8*)(Bp + ni * 16 * S_DIM + ks * 32);
            #pragma unroll
            for (int mi = 0; mi < 3; ++mi)
                #pragma unroll
                for (int ni = 0; ni < 4; ++ni)
                    acc[mi][ni] = __builtin_amdgcn_mfma_f32_16x16x32_bf16(
                        af[ks][mi], bfr[ni], acc[mi][ni], 0, 0, 0);
        }
        #pragma unroll
        for (int ni = 0; ni < 4; ++ni) {
            int c = n0h + ni * 16 + fr;
            float bv = b1[c];
            #pragma unroll
            for (int mi = 0; mi < 3; ++mi)
                #pragma unroll
                for (int r = 0; r < 4; ++r)
                    sH[(mi * 16 + q * 4 + r) * HPAD + c] =
                        f2bf(fmaxf(acc[mi][ni][r] + bv, 0.f));
        }
    }
    __syncthreads();

    // ---- layer 2: register double-buffered pipeline over 16 K-steps ----
    const short* Bp2 = W2T + (size_t)(wv * 64 + fr) * H_DIM + q * 8;
    f32x4 acc2[3][4] = {};
    bf16x8 bcur[4], bnxt[4], acur[3], anxt[3];

    #define LOAD_B(ks, dst)                                                   \
        _Pragma("unroll")                                                     \
        for (int ni = 0; ni < 4; ++ni)                                        \
            dst[ni] = *(const bf16x8*)(Bp2 + ni * 16 * H_DIM + (ks) * 32);
    #define LOAD_A(ks, dst)                                                   \
        _Pragma("unroll")                                                     \
        for (int mi = 0; mi < 3; ++mi) {                                      \
            const short* hp = &sH[(mi * 16 + fr) * HPAD + (ks) * 32 + q * 8]; \
            short4 lo = *(const short4*)hp;                                   \
            short4 hi = *(const short4*)(hp + 4);                             \
            bf16x8 v;                                                         \
            v[0] = lo.x; v[1] = lo.y; v[2] = lo.z; v[3] = lo.w;               \
            v[4] = hi.x; v[5] = hi.y; v[6] = hi.z; v[7] = hi.w;               \
            dst[mi] = v;                                                      \
        }

    LOAD_B(0, bcur);
    LOAD_A(0, acur);
    #pragma unroll
    for (int ks = 0; ks < 16; ++ks) {
        if (ks < 15) { LOAD_B(ks + 1, bnxt); LOAD_A(ks + 1, anxt); }
        #pragma unroll
        for (int mi = 0; mi < 3; ++mi)
            #pragma unroll
            for (int ni = 0; ni < 4; ++ni)
                acc2[mi][ni] = __builtin_amdgcn_mfma_f32_16x16x32_bf16(
                    acur[mi], bcur[ni], acc2[mi][ni], 0, 0, 0);
        if (ks < 15) {
            #pragma unroll
            for (int i = 0; i < 4; ++i) bcur[i] = bnxt[i];
            #pragma unroll
            for (int i = 0; i < 3; ++i) acur[i] = anxt[i];
        }
    }
    #undef LOAD_A
    #undef LOAD_B

    #pragma unroll
    for (int ni = 0; ni < 4; ++ni) {
        int c = wv * 64 + ni * 16 + fr;
        float bv = b2[c];
        #pragma unroll
        for (int mi = 0; mi < 3; ++mi)
            #pragma unroll
            for (int r = 0; r < 4; ++r) {
                int row = m0 + mi * 16 + q * 4 + r;
                out[(size_t)row * D_DIM + c] = acc2[mi][ni][r] + bv;
            }
    }
}

// ---------------------------------------------------------------------------
// Scoring (unchanged from round 3). One block (4 waves) per sample, 16-lane
// dots (4 rows in flight per wave), fast transcendental logsig.
// total_b = 2*( -logsig(clip(eu.ev)) - sum_k logsig(-clip(env_k.eu)) )
// ---------------------------------------------------------------------------
__device__ __forceinline__ float logsig_fast(float x) {
    float t = __expf(-fabsf(x));
    return fminf(x, 0.f) - __logf(1.f + t);
}
__device__ __forceinline__ float clip10(float x) {
    return fminf(fmaxf(x, -10.f), 10.f);
}
__device__ __forceinline__ float dot4(float4 a, float4 b) {
    return a.x * b.x + a.y * b.y + a.z * b.z + a.w * b.w;
}

__global__ __launch_bounds__(256) void score_kernel(
    const int*   __restrict__ pos_u,
    const int*   __restrict__ pos_v,
    const int*   __restrict__ neg_v,
    const float* __restrict__ u_emb,
    const float* __restrict__ v_emb,
    const float* __restrict__ tab_c,   // [MC_PAD][256] fp32
    const float* __restrict__ Ubuf,    // [MU_PAD][256] fp32
    float* __restrict__ partials)      // [B]
{
    const int b    = blockIdx.x;
    const int lane = threadIdx.x & 63;
    const int wv   = threadIdx.x >> 6;
    const int g    = lane >> 4;
    const int l    = lane & 15;

    int pu = pos_u[b];
    const float* eup = (pu < NR) ? u_emb + (size_t)pu * D_DIM
                                 : Ubuf  + (size_t)b  * D_DIM;
    float4 eu[4];
    #pragma unroll
    for (int j = 0; j < 4; ++j)
        eu[j] = *(const float4*)(eup + l * 16 + j * 4);

    float part = 0.f;
    const int* nv = neg_v + (size_t)b * K_NEG + wv * 8;

    #pragma unroll
    for (int it = 0; it < 2; ++it) {
        int ix = nv[it * 4 + g];
        const float* rp = (ix < NR) ? v_emb + (size_t)ix * D_DIM
                                    : tab_c + (size_t)(ix - NR) * D_DIM;
        float d = 0.f;
        #pragma unroll
        for (int j = 0; j < 4; ++j)
            d += dot4(eu[j], *(const float4*)(rp + l * 16 + j * 4));
        #pragma unroll
        for (int o = 1; o < 16; o <<= 1) d += __shfl_xor(d, o, 64);
        part -= logsig_fast(-clip10(d));
    }

    if (wv == 0) {
        int pv = pos_v[b];
        const float* rp = (pv < NR) ? v_emb + (size_t)pv * D_DIM
                                    : tab_c + (size_t)(pv - NR) * D_DIM;
        float d = 0.f;
        #pragma unroll
        for (int j = 0; j < 4; ++j)
            d += dot4(eu[j], *(const float4*)(rp + l * 16 + j * 4));
        #pragma unroll
        for (int o = 1; o < 16; o <<= 1) d += __shfl_xor(d, o, 64);
        float term = -logsig_fast(clip10(d));
        if (g == 0) part += term;
    }

    float ws = part;
    #pragma unroll
    for (int o = 32; o; o >>= 1) ws += __shfl_xor(ws, o, 64);
    __shared__ float sp[4];
    if (lane == 0) sp[wv] = ws * 0.0625f;
    __syncthreads();
    if (threadIdx.x == 0)
        partials[b] = sp[0] + sp[1] + sp[2] + sp[3];
}

__global__ __launch_bounds__(256) void reduce_kernel(
    const float* __restrict__ partials, float* __restrict__ out)
{
    float s = 0.f;
    for (int i = threadIdx.x; i < B_SIZE; i += 256) s += partials[i];
    #pragma unroll
    for (int o = 32; o; o >>= 1) s += __shfl_xor(s, o, 64);
    __shared__ float sp[4];
    if ((threadIdx.x & 63) == 0) sp[threadIdx.x >> 6] = s;
    __syncthreads();
    if (threadIdx.x == 0)
        out[0] = (sp[0] + sp[1] + sp[2] + sp[3]) * (2.0f / (float)B_SIZE);
}

// ---------------------------------------------------------------------------
extern "C" void kernel_launch(void* const* d_in, const int* in_sizes, int n_in,
                              void* d_out, int out_size, void* d_ws, size_t ws_size,
                              hipStream_t stream) {
    const int*   pos_u  = (const int*)  d_in[0];
    const int*   pos_v  = (const int*)  d_in[1];
    const int*   neg_v  = (const int*)  d_in[2];
    const float* u_emb  = (const float*)d_in[3];
    const float* v_emb  = (const float*)d_in[4];
    const float* stoich = (const float*)d_in[5];
    const float* tw1    = (const float*)d_in[6];
    const float* tb1    = (const float*)d_in[7];
    const float* tw2    = (const float*)d_in[8];
    const float* tb2    = (const float*)d_in[9];
    const float* cw1    = (const float*)d_in[10];
    const float* cb1    = (const float*)d_in[11];
    const float* cw2    = (const float*)d_in[12];
    const float* cb2    = (const float*)d_in[13];
    float* out = (float*)d_out;

    // workspace layout (bytes, 16B aligned)
    char* ws = (char*)d_ws;
    short* Xbf   = (short*)(ws);                      // MC_PAD*128*2 = 10,248,192
    short* Xu    = (short*)(ws + 10248192);           // MU_PAD*128*2 =  2,101,248
    short* W1T_t = (short*)(ws + 12349440);           //   512*128*2  =    131,072
    short* W1T_c = (short*)(ws + 12480512);           //                  131,072
    short* W2T_t = (short*)(ws + 12611584);           //   256*512*2  =    262,144
    short* W2T_c = (short*)(ws + 12873728);           //                  262,144
    float* tab_c = (float*)(ws + 13135872);           // MC_PAD*256*4 = 40,992,768
    float* Ubuf  = (float*)(ws + 54128640);           // MU_PAD*256*4 =  8,404,992
    float* parts = (float*)(ws + 62533632);           //  8192*4

    dim3 blk(256);

    // prep (3 launches)
    convert_x_kernel<<<dim3(MC_PAD * S_DIM / 4 / 256), blk, 0, stream>>>(stoich, Xbf);
    gather_xu_kernel<<<dim3(MU_PAD * S_DIM / 4 / 256), blk, 0, stream>>>(stoich, pos_u, Xu);
    transpose_all_kernel<<<dim3(393216 / 256), blk, 0, stream>>>(
        tw1, cw1, tw2, cw2, W1T_t, W1T_c, W2T_t, W2T_c);

    // both fused MLP passes in one launch (c-side: 834 blocks, u-side: 171)
    fused_mlp_kernel<<<dim3(CBLK + UBLK), blk, 0, stream>>>(
        Xbf, W1T_c, cb1, W2T_c, cb2, tab_c,
        Xu,  W1T_t, tb1, W2T_t, tb2, Ubuf);

    // scoring
    score_kernel<<<dim3(B_SIZE), blk, 0, stream>>>(pos_u, pos_v, neg_v,
                                                   u_emb, v_emb, tab_c, Ubuf, parts);
    reduce_kernel<<<dim3(1), blk, 0, stream>>>(parts, out);
}